// Round 1
// baseline (2019.592 us; speedup 1.0000x reference)
//
#include <hip/hip_runtime.h>
#include <math.h>

#define BB 8
#define NN 325
#define TT 24
#define DD 64
#define HH 8
#define MM 16
#define E2 128
#define DK 16
#define NEG 0.1f

// ---------------- K1: tfeat[b][m] = tanh(mean_t(tXin[b,0,t,:]) @ tproj_w + tproj_b)
__global__ void k_tfeat(const float* __restrict__ tXin, const float* __restrict__ tproj_w,
                        const float* __restrict__ tproj_b, float* __restrict__ tfeat) {
    int b = blockIdx.x;
    int d = threadIdx.x;  // 64 threads
    __shared__ float mv[DD];
    float a = 0.f;
    for (int t = 0; t < TT; ++t)
        a += tXin[((size_t)(b * NN + 0) * TT + t) * DD + d];
    mv[d] = a * (1.f / (float)TT);
    __syncthreads();
    if (d < MM) {
        float acc = tproj_b[d];
        for (int j = 0; j < DD; ++j) acc += mv[j] * tproj_w[j * MM + d];
        tfeat[b * MM + d] = tanhf(acc);
    }
}

// ---------------- K2: support = einsum('btnm,bmtd->bntd'); gcn_out = relu(support@gcn_w + b)
// grid: (B*T, ceil(N/64)) ; block 256
#define TN 64
#define MATPAD 331  // 331 % 32 = 11, gcd(11,32)=1 -> conflict-free row access
__global__ __launch_bounds__(256) void k_gcn(const float* __restrict__ matrix,
                                             const float* __restrict__ hidden,
                                             const float* __restrict__ gcn_w,
                                             const float* __restrict__ gcn_b,
                                             float* __restrict__ gcn_out) {
    int bt = blockIdx.x;          // 0..191
    int tile = blockIdx.y;        // 0..5
    int b = bt / TT, t = bt % TT;
    int n0 = tile * TN;

    __shared__ float s_mat[TN][MATPAD];
    __shared__ float s_H[64][DD];     // H chunk; reused to hold S at the end
    __shared__ float s_gw[DD][DD];

    int tid = threadIdx.x;
    for (int idx = tid; idx < DD * DD; idx += 256)
        s_gw[idx / DD][idx % DD] = gcn_w[idx];
    for (int idx = tid; idx < TN * MATPAD; idx += 256) {
        int r = idx / MATPAD, c = idx % MATPAD;
        int n = n0 + r;
        float v = 0.f;
        if (c < NN && n < NN) v = matrix[((size_t)(b * TT + t) * NN + n) * NN + c];
        s_mat[r][c] = v;
    }

    int r  = tid >> 3;          // 0..31  (owns rows r and r+32)
    int d0 = (tid & 7) << 3;    // 0,8,...,56 (owns 8 d's)
    float acc0[8], acc1[8];
#pragma unroll
    for (int i = 0; i < 8; ++i) { acc0[i] = 0.f; acc1[i] = 0.f; }

    for (int m0 = 0; m0 < NN; m0 += 64) {
        __syncthreads();
        for (int idx = tid; idx < 64 * DD; idx += 256) {
            int mm = idx >> 6, d = idx & 63;
            int m = m0 + mm;
            s_H[mm][d] = (m < NN) ? hidden[((size_t)(b * NN + m) * TT + t) * DD + d] : 0.f;
        }
        __syncthreads();
        int mmax = (NN - m0 < 64) ? (NN - m0) : 64;
        for (int mm = 0; mm < mmax; ++mm) {
            float w0 = s_mat[r][m0 + mm];
            float w1 = s_mat[r + 32][m0 + mm];
            float4 h0 = *(const float4*)&s_H[mm][d0];
            float4 h1 = *(const float4*)&s_H[mm][d0 + 4];
            acc0[0] += w0 * h0.x; acc0[1] += w0 * h0.y; acc0[2] += w0 * h0.z; acc0[3] += w0 * h0.w;
            acc0[4] += w0 * h1.x; acc0[5] += w0 * h1.y; acc0[6] += w0 * h1.z; acc0[7] += w0 * h1.w;
            acc1[0] += w1 * h0.x; acc1[1] += w1 * h0.y; acc1[2] += w1 * h0.z; acc1[3] += w1 * h0.w;
            acc1[4] += w1 * h1.x; acc1[5] += w1 * h1.y; acc1[6] += w1 * h1.z; acc1[7] += w1 * h1.w;
        }
    }

    // write S (support tile) into s_H
    __syncthreads();
    *(float4*)&s_H[r][d0]          = make_float4(acc0[0], acc0[1], acc0[2], acc0[3]);
    *(float4*)&s_H[r][d0 + 4]      = make_float4(acc0[4], acc0[5], acc0[6], acc0[7]);
    *(float4*)&s_H[r + 32][d0]     = make_float4(acc1[0], acc1[1], acc1[2], acc1[3]);
    *(float4*)&s_H[r + 32][d0 + 4] = make_float4(acc1[4], acc1[5], acc1[6], acc1[7]);
    __syncthreads();

    // gcn: out[n, e] = relu(b[e] + sum_d S[n][d]*gw[d][e])
    float g0[8], g1[8];
#pragma unroll
    for (int i = 0; i < 8; ++i) { g0[i] = gcn_b[d0 + i]; g1[i] = g0[i]; }
    for (int d = 0; d < DD; ++d) {
        float s0 = s_H[r][d], s1 = s_H[r + 32][d];
        float4 w0 = *(const float4*)&s_gw[d][d0];
        float4 w1 = *(const float4*)&s_gw[d][d0 + 4];
        g0[0] += s0 * w0.x; g0[1] += s0 * w0.y; g0[2] += s0 * w0.z; g0[3] += s0 * w0.w;
        g0[4] += s0 * w1.x; g0[5] += s0 * w1.y; g0[6] += s0 * w1.z; g0[7] += s0 * w1.w;
        g1[0] += s1 * w0.x; g1[1] += s1 * w0.y; g1[2] += s1 * w0.z; g1[3] += s1 * w0.w;
        g1[4] += s1 * w1.x; g1[5] += s1 * w1.y; g1[6] += s1 * w1.z; g1[7] += s1 * w1.w;
    }
#pragma unroll
    for (int i = 0; i < 8; ++i) {
        g0[i] = g0[i] > 0.f ? g0[i] : 0.f;
        g1[i] = g1[i] > 0.f ? g1[i] : 0.f;
    }
    if (n0 + r < NN) {
        size_t base = ((size_t)(b * NN + (n0 + r)) * TT + t) * DD;
        *(float4*)&gcn_out[base + d0]     = make_float4(g0[0], g0[1], g0[2], g0[3]);
        *(float4*)&gcn_out[base + d0 + 4] = make_float4(g0[4], g0[5], g0[6], g0[7]);
    }
    if (n0 + r + 32 < NN) {
        size_t base = ((size_t)(b * NN + (n0 + r + 32)) * TT + t) * DD;
        *(float4*)&gcn_out[base + d0]     = make_float4(g1[0], g1[1], g1[2], g1[3]);
        *(float4*)&gcn_out[base + d0 + 4] = make_float4(g1[4], g1[5], g1[6], g1[7]);
    }
}

// ---------------- K3: fused per-(b,n): build Wq/Wk/Wv, project, attention, out-proj, gate, residual
__global__ __launch_bounds__(256) void k_attn(
    const float* __restrict__ hidden, const float* __restrict__ tXin,
    const float* __restrict__ node_emb, const float* __restrict__ tfeat,
    const float* __restrict__ WQ, const float* __restrict__ WK, const float* __restrict__ WV,
    const float* __restrict__ out_w, const float* __restrict__ out_b,
    const float* __restrict__ gate_w, const float* __restrict__ gate_b,
    const float* __restrict__ gcn_out, float* __restrict__ out) {
    int bn = blockIdx.x;
    int b = bn / NN, n = bn % NN;
    int tid = threadIdx.x;

    __shared__ float s_W[E2 * E2];        // 64 KB: current emb-weighted weight
    __shared__ float s_qkv[TT][E2];       // 12 KB: input concat; reused as "val" after attention
    __shared__ float s_q[TT][E2];         // 12 KB
    __shared__ float s_k[TT][E2];         // 12 KB
    __shared__ float s_v[TT][E2];         // 12 KB
    __shared__ float s_value[TT][DD];     // 6 KB
    __shared__ float s_gcn[TT][DD];       // 6 KB
    __shared__ float s_e[MM];

    if (tid < MM) s_e[tid] = node_emb[n * MM + tid] * tfeat[b * MM + tid];

    const size_t base_bn = (size_t)(b * NN + n) * TT * DD;
    for (int idx = tid; idx < TT * E2; idx += 256) {
        int t = idx >> 7, i = idx & 127;
        s_qkv[t][i] = (i < DD) ? hidden[base_bn + t * DD + i] : tXin[base_bn + t * DD + (i - DD)];
    }
    for (int idx = tid; idx < TT * DD; idx += 256)
        s_gcn[idx >> 6][idx & 63] = gcn_out[base_bn + idx];
    __syncthreads();

    for (int p = 0; p < 3; ++p) {
        const float* W = (p == 0) ? WQ : ((p == 1) ? WK : WV);
        float(*dst)[E2] = (p == 0) ? s_q : ((p == 1) ? s_k : s_v);
        // weighted-sum: Wp[i][k] = sum_m e[m]*W[m][i][k]
        for (int idx = tid; idx < E2 * E2; idx += 256) {
            float a = 0.f;
#pragma unroll
            for (int m = 0; m < MM; ++m) a += s_e[m] * W[m * E2 * E2 + idx];
            s_W[idx] = a;
        }
        __syncthreads();
        // proj: dst[t][k] = lrelu(sum_i qkv[t][i]*Wp[i][k])
        for (int o = tid; o < TT * E2; o += 256) {
            int t = o >> 7, k2 = o & 127;
            float a = 0.f;
#pragma unroll 8
            for (int i = 0; i < E2; ++i) a += s_qkv[t][i] * s_W[i * E2 + k2];
            dst[t][k2] = (a >= 0.f) ? a : NEG * a;
        }
        __syncthreads();
    }

    // attention: one thread per (h,t) row; causal softmax fused with PV
    float* s_val = &s_qkv[0][0];  // qkv no longer needed
    if (tid < HH * TT) {
        int h = tid / TT, t = tid % TT;
        const float scale = 0.25f;  // 1/sqrt(DK)
        float sum = 0.f;
        float val[DK];
#pragma unroll
        for (int d = 0; d < DK; ++d) val[d] = 0.f;
        for (int s = 0; s <= t; ++s) {
            float dot = 0.f;
#pragma unroll
            for (int e = 0; e < DK; ++e) dot += s_q[t][h * DK + e] * s_k[s][h * DK + e];
            float w = __expf(dot * scale);  // |scale*dot| tiny: no max-subtraction needed
            sum += w;
#pragma unroll
            for (int d = 0; d < DK; ++d) val[d] += w * s_v[s][h * DK + d];
        }
        float inv = 1.f / sum;
#pragma unroll
        for (int d = 0; d < DK; ++d) s_val[t * E2 + h * DK + d] = val[d] * inv;
    }
    __syncthreads();

    // value = lrelu(val @ out_w + out_b)
    for (int o = tid; o < TT * DD; o += 256) {
        int t = o >> 6, dd = o & 63;
        float a = out_b[dd];
#pragma unroll 8
        for (int j = 0; j < E2; ++j) a += s_val[t * E2 + j] * out_w[j * DD + dd];
        s_value[t][dd] = (a >= 0.f) ? a : NEG * a;
    }
    __syncthreads();

    // gate + residual
    for (int o = tid; o < TT * DD; o += 256) {
        int t = o >> 6, dd = o & 63;
        float zz = gate_b[dd];
#pragma unroll 8
        for (int j = 0; j < DD; ++j) zz += s_gcn[t][j] * gate_w[j * DD + dd];
#pragma unroll 8
        for (int j = 0; j < DD; ++j) zz += s_value[t][j] * gate_w[(DD + j) * DD + dd];
        float z = 1.f / (1.f + __expf(-zz));
        float g = s_gcn[t][dd], vv = s_value[t][dd];
        out[base_bn + o] = z * g + (1.f - z) * vv + hidden[base_bn + o];
    }
}

extern "C" void kernel_launch(void* const* d_in, const int* in_sizes, int n_in,
                              void* d_out, int out_size, void* d_ws, size_t ws_size,
                              hipStream_t stream) {
    const float* hidden   = (const float*)d_in[0];
    const float* tXin     = (const float*)d_in[1];
    const float* matrix   = (const float*)d_in[2];
    const float* gcn_w    = (const float*)d_in[3];
    const float* gcn_b    = (const float*)d_in[4];
    const float* node_emb = (const float*)d_in[5];
    const float* tproj_w  = (const float*)d_in[6];
    const float* tproj_b  = (const float*)d_in[7];
    const float* WK_      = (const float*)d_in[8];   // NOTE dict order: WK, WQ, WV
    const float* WQ_      = (const float*)d_in[9];
    const float* WV_      = (const float*)d_in[10];
    const float* out_w    = (const float*)d_in[11];
    const float* out_b    = (const float*)d_in[12];
    const float* gate_w   = (const float*)d_in[13];
    const float* gate_b   = (const float*)d_in[14];
    float* out = (float*)d_out;

    float* tfeat   = (float*)d_ws;          // 128 floats
    float* gcn_out = tfeat + 128;           // B*N*T*D floats (~16 MB)

    k_tfeat<<<BB, DD, 0, stream>>>(tXin, tproj_w, tproj_b, tfeat);
    k_gcn<<<dim3(BB * TT, (NN + TN - 1) / TN), 256, 0, stream>>>(matrix, hidden, gcn_w, gcn_b, gcn_out);
    k_attn<<<BB * NN, 256, 0, stream>>>(hidden, tXin, node_emb, tfeat, WQ_, WK_, WV_,
                                        out_w, out_b, gate_w, gate_b, gcn_out, out);
}

// Round 2
// 1725.198 us; speedup vs baseline: 1.1706x; 1.1706x over previous
//
#include <hip/hip_runtime.h>
#include <math.h>

#define BB 8
#define NN 325
#define TT 24
#define DD 64
#define HH 8
#define MM 16
#define E2 128
#define DK 16
#define NEG 0.1f

#define GG 2
#define NB ((NN + GG - 1) / GG)   // 163 node-pairs
#define PADE 132                  // row stride (floats) for 128-wide LDS rows: (132*t)%32 = 4t -> spreads banks

// ---------------- K1: tfeat[b][m] = tanh(mean_t(tXin[b,0,t,:]) @ tproj_w + tproj_b)
__global__ void k_tfeat(const float* __restrict__ tXin, const float* __restrict__ tproj_w,
                        const float* __restrict__ tproj_b, float* __restrict__ tfeat) {
    int b = blockIdx.x;
    int d = threadIdx.x;  // 64 threads
    __shared__ float mv[DD];
    float a = 0.f;
    for (int t = 0; t < TT; ++t)
        a += tXin[((size_t)(b * NN + 0) * TT + t) * DD + d];
    mv[d] = a * (1.f / (float)TT);
    __syncthreads();
    if (d < MM) {
        float acc = tproj_b[d];
        for (int j = 0; j < DD; ++j) acc += mv[j] * tproj_w[j * MM + d];
        tfeat[b * MM + d] = tanhf(acc);
    }
}

// ---------------- K2: support = einsum('btnm,bmtd->bntd'); gcn_out = relu(support@gcn_w + b)
// grid: (B*T, ceil(N/64)) ; block 256 ; LDS ~49KB -> 3 blocks/CU
#define TN 64
__global__ __launch_bounds__(256) void k_gcn(const float* __restrict__ matrix,
                                             const float* __restrict__ hidden,
                                             const float* __restrict__ gcn_w,
                                             const float* __restrict__ gcn_b,
                                             float* __restrict__ gcn_out) {
    int bt = blockIdx.x;          // 0..191
    int tile = blockIdx.y;        // 0..5
    int b = bt / TT, t = bt % TT;
    int n0 = tile * TN;

    __shared__ float s_mat[TN][68];   // 64x64 tile, stride 68 -> bank = (4r+mm)%32, conflict-free
    __shared__ float s_H[64][DD];     // H chunk; reused to hold S at the end
    __shared__ float s_gw[DD][DD];

    int tid = threadIdx.x;
    for (int idx = tid; idx < DD * DD; idx += 256)
        s_gw[idx / DD][idx % DD] = gcn_w[idx];

    int r  = tid >> 3;          // 0..31  (owns rows r and r+32)
    int d0 = (tid & 7) << 3;    // 0,8,...,56 (owns 8 d's)
    float acc0[8], acc1[8];
#pragma unroll
    for (int i = 0; i < 8; ++i) { acc0[i] = 0.f; acc1[i] = 0.f; }

    for (int m0 = 0; m0 < NN; m0 += 64) {
        __syncthreads();
        // load matrix tile [64 rows n][64 cols m]
        for (int idx = tid; idx < TN * 64; idx += 256) {
            int rr = idx >> 6, cc = idx & 63;
            int n = n0 + rr, m = m0 + cc;
            s_mat[rr][cc] = (n < NN && m < NN) ? matrix[((size_t)(b * TT + t) * NN + n) * NN + m] : 0.f;
        }
        // load H tile
        for (int idx = tid; idx < 64 * DD; idx += 256) {
            int mm = idx >> 6, d = idx & 63;
            int m = m0 + mm;
            s_H[mm][d] = (m < NN) ? hidden[((size_t)(b * NN + m) * TT + t) * DD + d] : 0.f;
        }
        __syncthreads();
        int mmax = (NN - m0 < 64) ? (NN - m0) : 64;
        for (int mm = 0; mm < mmax; ++mm) {
            float w0 = s_mat[r][mm];
            float w1 = s_mat[r + 32][mm];
            float4 h0 = *(const float4*)&s_H[mm][d0];
            float4 h1 = *(const float4*)&s_H[mm][d0 + 4];
            acc0[0] += w0 * h0.x; acc0[1] += w0 * h0.y; acc0[2] += w0 * h0.z; acc0[3] += w0 * h0.w;
            acc0[4] += w0 * h1.x; acc0[5] += w0 * h1.y; acc0[6] += w0 * h1.z; acc0[7] += w0 * h1.w;
            acc1[0] += w1 * h0.x; acc1[1] += w1 * h0.y; acc1[2] += w1 * h0.z; acc1[3] += w1 * h0.w;
            acc1[4] += w1 * h1.x; acc1[5] += w1 * h1.y; acc1[6] += w1 * h1.z; acc1[7] += w1 * h1.w;
        }
    }

    // write S (support tile) into s_H
    __syncthreads();
    *(float4*)&s_H[r][d0]          = make_float4(acc0[0], acc0[1], acc0[2], acc0[3]);
    *(float4*)&s_H[r][d0 + 4]      = make_float4(acc0[4], acc0[5], acc0[6], acc0[7]);
    *(float4*)&s_H[r + 32][d0]     = make_float4(acc1[0], acc1[1], acc1[2], acc1[3]);
    *(float4*)&s_H[r + 32][d0 + 4] = make_float4(acc1[4], acc1[5], acc1[6], acc1[7]);
    __syncthreads();

    // gcn: out[n, e] = relu(b[e] + sum_d S[n][d]*gw[d][e])
    float g0[8], g1[8];
#pragma unroll
    for (int i = 0; i < 8; ++i) { g0[i] = gcn_b[d0 + i]; g1[i] = g0[i]; }
    for (int d = 0; d < DD; ++d) {
        float s0 = s_H[r][d], s1 = s_H[r + 32][d];
        float4 w0 = *(const float4*)&s_gw[d][d0];
        float4 w1 = *(const float4*)&s_gw[d][d0 + 4];
        g0[0] += s0 * w0.x; g0[1] += s0 * w0.y; g0[2] += s0 * w0.z; g0[3] += s0 * w0.w;
        g0[4] += s0 * w1.x; g0[5] += s0 * w1.y; g0[6] += s0 * w1.z; g0[7] += s0 * w1.w;
        g1[0] += s1 * w0.x; g1[1] += s1 * w0.y; g1[2] += s1 * w0.z; g1[3] += s1 * w0.w;
        g1[4] += s1 * w1.x; g1[5] += s1 * w1.y; g1[6] += s1 * w1.z; g1[7] += s1 * w1.w;
    }
#pragma unroll
    for (int i = 0; i < 8; ++i) {
        g0[i] = g0[i] > 0.f ? g0[i] : 0.f;
        g1[i] = g1[i] > 0.f ? g1[i] : 0.f;
    }
    if (n0 + r < NN) {
        size_t base = ((size_t)(b * NN + (n0 + r)) * TT + t) * DD;
        *(float4*)&gcn_out[base + d0]     = make_float4(g0[0], g0[1], g0[2], g0[3]);
        *(float4*)&gcn_out[base + d0 + 4] = make_float4(g0[4], g0[5], g0[6], g0[7]);
    }
    if (n0 + r + 32 < NN) {
        size_t base = ((size_t)(b * NN + (n0 + r + 32)) * TT + t) * DD;
        *(float4*)&gcn_out[base + d0]     = make_float4(g1[0], g1[1], g1[2], g1[3]);
        *(float4*)&gcn_out[base + d0 + 4] = make_float4(g1[4], g1[5], g1[6], g1[7]);
    }
}

// ---------------- K3: fused per-(b, 2 nodes): on-the-fly Wp columns, attention, out-proj, gate, residual
// block = 384 threads (3 proj x 128 cols). LDS ~74KB -> 2 blocks/CU.
__global__ __launch_bounds__(384, 3) void k_attn(
    const float* __restrict__ hidden, const float* __restrict__ tXin,
    const float* __restrict__ node_emb, const float* __restrict__ tfeat,
    const float* __restrict__ WQ, const float* __restrict__ WK, const float* __restrict__ WV,
    const float* __restrict__ out_w, const float* __restrict__ out_b,
    const float* __restrict__ gate_w, const float* __restrict__ gate_b,
    const float* __restrict__ gcn_out, float* __restrict__ out) {
    int bn = blockIdx.x;
    int b = bn / NB, n0 = (bn % NB) * GG;
    int tid = threadIdx.x;

    __shared__ float s_in[GG][TT][PADE];   // qkv concat inputs; reused as "val" per g
    __shared__ float s_q[TT][PADE];
    __shared__ float s_k[TT][PADE];
    __shared__ float s_v[TT][PADE];
    __shared__ float s_gcn[TT][DD];
    __shared__ float s_value[TT][DD];
    __shared__ float s_e[GG][MM];

    // ---- phase 0: emb coeffs + inputs
    if (tid < GG * MM) {
        int g = tid / MM, m = tid % MM;
        int n = n0 + g;
        s_e[g][m] = (n < NN) ? node_emb[n * MM + m] * tfeat[b * MM + m] : 0.f;
    }
    for (int idx = tid; idx < GG * TT * E2; idx += 384) {
        int g = idx / (TT * E2);
        int rr = idx % (TT * E2);
        int t = rr >> 7, i = rr & 127;
        int n = n0 + g;
        float v = 0.f;
        if (n < NN) {
            size_t base = ((size_t)(b * NN + n) * TT + t) * DD;
            v = (i < DD) ? hidden[base + i] : tXin[base + (i - DD)];
        }
        s_in[g][t][i] = v;
    }
    __syncthreads();

    // ---- column loop: thread (p,k) computes proj column k of projection p for both nodes, all t
    int p = tid >> 7;          // 0=Q 1=K 2=V, wave-uniform
    int k = tid & 127;
    const float* __restrict__ W = (p == 0) ? WQ : ((p == 1) ? WK : WV);

    float e0r[MM], e1r[MM];
#pragma unroll
    for (int m = 0; m < MM; ++m) { e0r[m] = s_e[0][m]; e1r[m] = s_e[1][m]; }

    float acc0[TT], acc1[TT];
#pragma unroll
    for (int t = 0; t < TT; ++t) { acc0[t] = 0.f; acc1[t] = 0.f; }

    for (int i0 = 0; i0 < E2; i0 += 4) {
        float wp0[4] = {0.f, 0.f, 0.f, 0.f};
        float wp1[4] = {0.f, 0.f, 0.f, 0.f};
#pragma unroll
        for (int m = 0; m < MM; ++m) {
#pragma unroll
            for (int ii = 0; ii < 4; ++ii) {
                float w = W[(size_t)m * E2 * E2 + (size_t)(i0 + ii) * E2 + k];
                wp0[ii] += e0r[m] * w;
                wp1[ii] += e1r[m] * w;
            }
        }
#pragma unroll
        for (int t = 0; t < TT; ++t) {
            const float4 x0 = *(const float4*)&s_in[0][t][i0];
            const float4 x1 = *(const float4*)&s_in[1][t][i0];
            acc0[t] += x0.x * wp0[0] + x0.y * wp0[1] + x0.z * wp0[2] + x0.w * wp0[3];
            acc1[t] += x1.x * wp1[0] + x1.y * wp1[1] + x1.z * wp1[2] + x1.w * wp1[3];
        }
    }

    // ---- per node: qkv -> attention -> out-proj -> gate -> residual
#pragma unroll
    for (int g = 0; g < GG; ++g) {
        bool valid = (n0 + g < NN);
        float* dst = (p == 0) ? &s_q[0][0] : ((p == 1) ? &s_k[0][0] : &s_v[0][0]);
        if (valid) {
#pragma unroll
            for (int t = 0; t < TT; ++t) {
                float a = (g == 0) ? acc0[t] : acc1[t];
                dst[t * PADE + k] = (a >= 0.f) ? a : NEG * a;
            }
        }
        __syncthreads();

        if (valid) {
            if (tid < HH * TT) {
                // attention row (h,t): causal softmax fused with PV
                int h = tid / TT, t = tid % TT;
                const float scale = 0.25f;  // 1/sqrt(16)
                float4 q0 = *(const float4*)&s_q[t][h * DK];
                float4 q1 = *(const float4*)&s_q[t][h * DK + 4];
                float4 q2 = *(const float4*)&s_q[t][h * DK + 8];
                float4 q3 = *(const float4*)&s_q[t][h * DK + 12];
                float sum = 0.f;
                float val[DK];
#pragma unroll
                for (int d = 0; d < DK; ++d) val[d] = 0.f;
                for (int s = 0; s <= t; ++s) {
                    float4 k0 = *(const float4*)&s_k[s][h * DK];
                    float4 k1 = *(const float4*)&s_k[s][h * DK + 4];
                    float4 k2 = *(const float4*)&s_k[s][h * DK + 8];
                    float4 k3 = *(const float4*)&s_k[s][h * DK + 12];
                    float dot = q0.x * k0.x + q0.y * k0.y + q0.z * k0.z + q0.w * k0.w
                              + q1.x * k1.x + q1.y * k1.y + q1.z * k1.z + q1.w * k1.w
                              + q2.x * k2.x + q2.y * k2.y + q2.z * k2.z + q2.w * k2.w
                              + q3.x * k3.x + q3.y * k3.y + q3.z * k3.z + q3.w * k3.w;
                    float w = __expf(dot * scale);
                    sum += w;
                    float4 v0 = *(const float4*)&s_v[s][h * DK];
                    float4 v1 = *(const float4*)&s_v[s][h * DK + 4];
                    float4 v2 = *(const float4*)&s_v[s][h * DK + 8];
                    float4 v3 = *(const float4*)&s_v[s][h * DK + 12];
                    val[0] += w * v0.x;  val[1] += w * v0.y;  val[2] += w * v0.z;  val[3] += w * v0.w;
                    val[4] += w * v1.x;  val[5] += w * v1.y;  val[6] += w * v1.z;  val[7] += w * v1.w;
                    val[8] += w * v2.x;  val[9] += w * v2.y;  val[10] += w * v2.z; val[11] += w * v2.w;
                    val[12] += w * v3.x; val[13] += w * v3.y; val[14] += w * v3.z; val[15] += w * v3.w;
                }
                float inv = 1.f / sum;
#pragma unroll
                for (int d = 0; d < DK; ++d) s_in[g][t][h * DK + d] = val[d] * inv;  // s_in[g] reused as val
            } else {
                // remaining 192 threads: stage gcn_out for this node
                size_t base = (size_t)(b * NN + n0 + g) * TT * DD;
                for (int idx = tid - 192; idx < TT * DD; idx += 192)
                    s_gcn[idx >> 6][idx & 63] = gcn_out[base + idx];
            }
        }
        __syncthreads();

        if (valid) {
            // value = lrelu(val @ out_w + out_b)
            for (int o = tid; o < TT * DD; o += 384) {
                int t = o >> 6, dd = o & 63;
                float a = out_b[dd];
#pragma unroll 8
                for (int j = 0; j < E2; ++j) a += s_in[g][t][j] * out_w[j * DD + dd];
                s_value[t][dd] = (a >= 0.f) ? a : NEG * a;
            }
        }
        __syncthreads();

        if (valid) {
            size_t base = (size_t)(b * NN + n0 + g) * TT * DD;
            for (int o = tid; o < TT * DD; o += 384) {
                int t = o >> 6, dd = o & 63;
                float zz = gate_b[dd];
#pragma unroll 8
                for (int j = 0; j < DD; ++j) zz += s_gcn[t][j] * gate_w[j * DD + dd];
#pragma unroll 8
                for (int j = 0; j < DD; ++j) zz += s_value[t][j] * gate_w[(DD + j) * DD + dd];
                float z = 1.f / (1.f + __expf(-zz));
                float gg = s_gcn[t][dd], vv = s_value[t][dd];
                out[base + o] = z * gg + (1.f - z) * vv + hidden[base + o];
            }
        }
        __syncthreads();
    }
}

extern "C" void kernel_launch(void* const* d_in, const int* in_sizes, int n_in,
                              void* d_out, int out_size, void* d_ws, size_t ws_size,
                              hipStream_t stream) {
    const float* hidden   = (const float*)d_in[0];
    const float* tXin     = (const float*)d_in[1];
    const float* matrix   = (const float*)d_in[2];
    const float* gcn_w    = (const float*)d_in[3];
    const float* gcn_b    = (const float*)d_in[4];
    const float* node_emb = (const float*)d_in[5];
    const float* tproj_w  = (const float*)d_in[6];
    const float* tproj_b  = (const float*)d_in[7];
    const float* WK_      = (const float*)d_in[8];   // dict order: WK, WQ, WV
    const float* WQ_      = (const float*)d_in[9];
    const float* WV_      = (const float*)d_in[10];
    const float* out_w    = (const float*)d_in[11];
    const float* out_b    = (const float*)d_in[12];
    const float* gate_w   = (const float*)d_in[13];
    const float* gate_b   = (const float*)d_in[14];
    float* out = (float*)d_out;

    float* tfeat   = (float*)d_ws;          // 128 floats
    float* gcn_out = tfeat + 128;           // B*N*T*D floats (~16 MB)

    k_tfeat<<<BB, DD, 0, stream>>>(tXin, tproj_w, tproj_b, tfeat);
    k_gcn<<<dim3(BB * TT, (NN + TN - 1) / TN), 256, 0, stream>>>(matrix, hidden, gcn_w, gcn_b, gcn_out);
    k_attn<<<BB * NB, 384, 0, stream>>>(hidden, tXin, node_emb, tfeat, WQ_, WK_, WV_,
                                        out_w, out_b, gate_w, gate_b, gcn_out, out);
}